// Round 5
// baseline (70.290 us; speedup 1.0000x reference)
//
#include <hip/hip_runtime.h>
#include <hip/hip_bf16.h>

// ROI Align fp32, NCHW input (B=2, C=256, H=W=200), pooled 7x7, SAMPLE_NUM=2,
// SPATIAL_SCALE=0.25, ROI_END_MODE=1.
//
// Round 5: gather is L3-BW-bound (~10 TB/s serving ~400 MB of requests with
// ~10x pixel reuse scattered across XCDs). Add:
//   (a) one-block bitonic sort of ROIs by (batch, Morton(center_y, center_x))
//   (b) chunked XCD block mapping (rank = (bid%8)*chunk + bid/8) so each
//       XCD's non-coherent L2 sees a spatially clustered ~125-ROI working set
//       (~2.5-5 MB) -> pixel reuse resolves in L2 (34.5 TB/s) not L3 (~10).
// Pipeline:
//   Phase 0: roi_sort_kernel -> perm[] in d_ws (after featT region)
//   Phase 1: NCHW fp32 -> NHWC bf16 transpose into d_ws (41 MB, L3-resident)
//   Phase 2: gather (512 thr / ROI), fp32 accumulate, LDS-staged linear store

constexpr int C_TOT  = 256;
constexpr int H_FEAT = 200;
constexpr int W_FEAT = 200;
constexpr int HW     = H_FEAT * W_FEAT;
constexpr int S_TOT  = 49;             // 7*7 pooled cells
constexpr size_t FEATT_BYTES = (size_t)2 * HW * C_TOT * sizeof(unsigned short); // 40.96 MB
constexpr int NXCD = 8;

// ---------------------------------------------------------------- ROI sort
// Single block, 1024 threads, bitonic sort of up to 1024 (key, idx) pairs.
__global__ __launch_bounds__(1024) void roi_sort_kernel(
    const float* __restrict__ rois, int* __restrict__ perm, int N)
{
    __shared__ unsigned int skey[1024];
    __shared__ unsigned short sval[1024];
    int t = threadIdx.x;

    unsigned int key = 0xFFFFFFFFu;
    if (t < N) {
        const float* r = rois + (size_t)t * 5;
        int   b  = (int)r[0];
        float cx = (r[1] + r[3]) * 0.5f * 0.25f;   // feature-space center
        float cy = (r[2] + r[4]) * 0.5f * 0.25f;
        unsigned int ix = (unsigned int)min(max((int)cx, 0), W_FEAT - 1);
        unsigned int iy = (unsigned int)min(max((int)cy, 0), H_FEAT - 1);
        unsigned int m = 0;
        #pragma unroll
        for (int i = 0; i < 8; ++i) {
            m |= ((ix >> i) & 1u) << (2 * i);
            m |= ((iy >> i) & 1u) << (2 * i + 1);
        }
        key = ((unsigned int)b << 16) | m;
    }
    skey[t] = key;
    sval[t] = (unsigned short)t;
    __syncthreads();

    for (int k = 2; k <= 1024; k <<= 1) {
        for (int j = k >> 1; j > 0; j >>= 1) {
            int p = t ^ j;
            if (p > t) {
                bool up = ((t & k) == 0);
                unsigned int a = skey[t], c = skey[p];
                if ((a > c) == up) {
                    skey[t] = c; skey[p] = a;
                    unsigned short va = sval[t], vc = sval[p];
                    sval[t] = vc; sval[p] = va;
                }
            }
            __syncthreads();
        }
    }
    if (t < N) perm[t] = (int)sval[t];
}

// ---------------------------------------------------------------- transpose
// feat[b][c][s] (fp32) -> featT[b][s][c] (bf16, RNE).
__global__ __launch_bounds__(256) void nchw_to_nhwc_bf16_kernel(
    const float* __restrict__ feat,
    unsigned short* __restrict__ featT)
{
    __shared__ float tile[32][33];
    int tx = threadIdx.x;        // 0..31
    int ty = threadIdx.y;        // 0..7
    int s0 = blockIdx.x * 32;
    int c0 = blockIdx.y * 32;
    int b  = blockIdx.z;

    const float* src = feat + ((size_t)b * C_TOT) * HW;
    #pragma unroll
    for (int i = 0; i < 4; ++i) {
        int r = ty + i * 8;      // channel within tile
        tile[r][tx] = src[(size_t)(c0 + r) * HW + (s0 + tx)];
    }
    __syncthreads();
    unsigned short* dst = featT + ((size_t)b * HW) * C_TOT;
    #pragma unroll
    for (int i = 0; i < 4; ++i) {
        int r = ty + i * 8;      // spatial within tile
        float x = tile[tx][r];
        unsigned int u = __float_as_uint(x);
        unsigned int rb = (u + 0x7fffu + ((u >> 16) & 1u)) >> 16;   // RNE
        dst[(size_t)(s0 + r) * C_TOT + (c0 + tx)] = (unsigned short)rb;
    }
}

// ---------------------------------------------------------------- gather
__global__ __launch_bounds__(512) void roi_align_nhwc_kernel(
    const unsigned short* __restrict__ featT,
    const float* __restrict__ rois,
    const int* __restrict__ perm,
    float* __restrict__ out,
    int N, int use_perm)
{
    __shared__ alignas(16) float tile[C_TOT * S_TOT];   // [c][s] == output order

    int n;
    if (use_perm) {
        // chunked XCD transform: XCD x gets sorted ranks [x*chunk, (x+1)*chunk)
        int chunk = (N + NXCD - 1) / NXCD;
        int rank  = (blockIdx.x & (NXCD - 1)) * chunk + (blockIdx.x >> 3);
        if (rank >= N) rank = blockIdx.x;
        n = perm[rank];
    } else {
        n = blockIdx.x;
    }

    int tid  = threadIdx.x;
    int wave = tid >> 6;         // 0..7
    int lane = tid & 63;

    const float* r = rois + (size_t)n * 5;
    int   b  = (int)r[0];
    float x1 = r[1] * 0.25f;
    float y1 = r[2] * 0.25f;
    float x2 = (r[3] + 1.0f) * 0.25f;
    float y2 = (r[4] + 1.0f) * 0.25f;
    float bin_w = fmaxf(x2 - x1, 1.0f) * (1.0f / 7.0f);
    float bin_h = fmaxf(y2 - y1, 1.0f) * (1.0f / 7.0f);

    const unsigned short* fbase =
        featT + (size_t)b * HW * C_TOT + (size_t)lane * 4;

    for (int s = wave; s < S_TOT; s += 8) {
        int ph = s / 7;
        int pw = s - ph * 7;

        int   yoff[2][2];
        int   xoff[2][2];
        float wy[2][2], wx[2][2];
        #pragma unroll
        for (int i = 0; i < 2; ++i) {
            float gy  = (float)(2 * ph + i);
            float cy  = y1 + bin_h * ((gy + 0.5f) * 0.5f);
            bool  vy  = (cy >= -1.0f) && (cy <= (float)H_FEAT);
            float ccy = fminf(fmaxf(cy, 0.0f), (float)(H_FEAT - 1));
            int   ylo = (int)ccy;
            int   yhi = min(ylo + 1, H_FEAT - 1);
            float fy  = ccy - (float)ylo;
            yoff[i][0] = ylo * W_FEAT;
            yoff[i][1] = yhi * W_FEAT;
            // fold 0.5 per axis -> product carries the 0.25 sample-average
            wy[i][0] = vy ? (1.0f - fy) * 0.5f : 0.0f;
            wy[i][1] = vy ? fy * 0.5f          : 0.0f;

            float gx  = (float)(2 * pw + i);
            float cx  = x1 + bin_w * ((gx + 0.5f) * 0.5f);
            bool  vx  = (cx >= -1.0f) && (cx <= (float)W_FEAT);
            float ccx = fminf(fmaxf(cx, 0.0f), (float)(W_FEAT - 1));
            int   xlo = (int)ccx;
            int   xhi = min(xlo + 1, W_FEAT - 1);
            float fx  = ccx - (float)xlo;
            xoff[i][0] = xlo;
            xoff[i][1] = xhi;
            wx[i][0] = vx ? (1.0f - fx) * 0.5f : 0.0f;
            wx[i][1] = vx ? fx * 0.5f          : 0.0f;
        }

        float4 acc = make_float4(0.f, 0.f, 0.f, 0.f);
        #pragma unroll
        for (int iy = 0; iy < 2; ++iy)
        #pragma unroll
        for (int jy = 0; jy < 2; ++jy)
        #pragma unroll
        for (int ix = 0; ix < 2; ++ix)
        #pragma unroll
        for (int jx = 0; jx < 2; ++jx) {
            float w = wy[iy][jy] * wx[ix][jx];
            const ushort4 v = *reinterpret_cast<const ushort4*>(
                fbase + (size_t)(yoff[iy][jy] + xoff[ix][jx]) * C_TOT);
            float f0 = __uint_as_float((unsigned int)v.x << 16);
            float f1 = __uint_as_float((unsigned int)v.y << 16);
            float f2 = __uint_as_float((unsigned int)v.z << 16);
            float f3 = __uint_as_float((unsigned int)v.w << 16);
            acc.x = fmaf(w, f0, acc.x);
            acc.y = fmaf(w, f1, acc.y);
            acc.z = fmaf(w, f2, acc.z);
            acc.w = fmaf(w, f3, acc.w);
        }

        int c = lane * 4;
        tile[(c + 0) * S_TOT + s] = acc.x;
        tile[(c + 1) * S_TOT + s] = acc.y;
        tile[(c + 2) * S_TOT + s] = acc.z;
        tile[(c + 3) * S_TOT + s] = acc.w;
    }
    __syncthreads();

    // Linear float4 store: tile flat layout == out[n] flat layout.
    const float4* t4 = reinterpret_cast<const float4*>(tile);
    float4* o4 = reinterpret_cast<float4*>(out + (size_t)n * (C_TOT * S_TOT));
    constexpr int Q = C_TOT * S_TOT / 4;   // 3136
    for (int q = tid; q < Q; q += 512)
        o4[q] = t4[q];
}

// ---------------------------------------------------------------- fp32 fallback
constexpr int CPT = 4;
constexpr int CG  = C_TOT / CPT;

__global__ __launch_bounds__(256) void roi_align_direct_kernel(
    const float* __restrict__ feat,
    const float* __restrict__ rois,
    float* __restrict__ out,
    int N)
{
    int t = blockIdx.x * 256 + threadIdx.x;
    int total = N * CG * S_TOT;
    if (t >= total) return;

    int s   = t % S_TOT;
    int rem = t / S_TOT;
    int c0  = rem % CG;
    int n   = rem / CG;
    int ph  = s / 7;
    int pw  = s - ph * 7;

    const float* r = rois + (size_t)n * 5;
    int   b  = (int)r[0];
    float x1 = r[1] * 0.25f;
    float y1 = r[2] * 0.25f;
    float x2 = (r[3] + 1.0f) * 0.25f;
    float y2 = (r[4] + 1.0f) * 0.25f;
    float bin_w = fmaxf(x2 - x1, 1.0f) * (1.0f / 7.0f);
    float bin_h = fmaxf(y2 - y1, 1.0f) * (1.0f / 7.0f);

    int   roff[2][2], coff[2][2];
    float wy[2][2], wx[2][2];
    #pragma unroll
    for (int i = 0; i < 2; ++i) {
        float gy  = (float)(2 * ph + i);
        float cy  = y1 + bin_h * ((gy + 0.5f) * 0.5f);
        bool  vy  = (cy >= -1.0f) && (cy <= (float)H_FEAT);
        float ccy = fminf(fmaxf(cy, 0.0f), (float)(H_FEAT - 1));
        int   ylo = (int)ccy;
        int   yhi = min(ylo + 1, H_FEAT - 1);
        float fy  = ccy - (float)ylo;
        roff[i][0] = ylo * W_FEAT;
        roff[i][1] = yhi * W_FEAT;
        wy[i][0] = vy ? (1.0f - fy) : 0.0f;
        wy[i][1] = vy ? fy          : 0.0f;

        float gx  = (float)(2 * pw + i);
        float cx  = x1 + bin_w * ((gx + 0.5f) * 0.5f);
        bool  vx  = (cx >= -1.0f) && (cx <= (float)W_FEAT);
        float ccx = fminf(fmaxf(cx, 0.0f), (float)(W_FEAT - 1));
        int   xlo = (int)ccx;
        int   xhi = min(xlo + 1, W_FEAT - 1);
        float fx  = ccx - (float)xlo;
        coff[i][0] = xlo;
        coff[i][1] = xhi;
        wx[i][0] = vx ? (1.0f - fx) : 0.0f;
        wx[i][1] = vx ? fx          : 0.0f;
    }

    float w16[16];
    int   o16[16];
    #pragma unroll
    for (int iy = 0; iy < 2; ++iy)
    #pragma unroll
    for (int ix = 0; ix < 2; ++ix)
    #pragma unroll
    for (int jy = 0; jy < 2; ++jy)
    #pragma unroll
    for (int jx = 0; jx < 2; ++jx) {
        int idx = ((iy * 2 + ix) * 2 + jy) * 2 + jx;
        w16[idx] = wy[iy][jy] * wx[ix][jx];
        o16[idx] = roff[iy][jy] + coff[ix][jx];
    }

    size_t base  = ((size_t)b * C_TOT + c0) * HW;
    size_t obase = (size_t)n * (C_TOT * S_TOT) + (size_t)c0 * S_TOT + s;

    #pragma unroll
    for (int k = 0; k < CPT; ++k) {
        const float* f = feat + base + (size_t)k * CG * HW;
        float acc = 0.0f;
        #pragma unroll
        for (int j = 0; j < 16; ++j)
            acc = fmaf(w16[j], f[o16[j]], acc);
        out[obase + (size_t)k * (CG * S_TOT)] = acc * 0.25f;
    }
}

extern "C" void kernel_launch(void* const* d_in, const int* in_sizes, int n_in,
                              void* d_out, int out_size, void* d_ws, size_t ws_size,
                              hipStream_t stream) {
    const float* feat = (const float*)d_in[0];
    const float* rois = (const float*)d_in[1];
    float* out = (float*)d_out;
    int N = in_sizes[1] / 5;

    size_t need = FEATT_BYTES + 4096;
    if (ws_size >= need) {
        unsigned short* featT = (unsigned short*)d_ws;
        int* perm = (int*)((char*)d_ws + FEATT_BYTES);
        int use_perm = (N <= 1024) ? 1 : 0;
        if (use_perm)
            roi_sort_kernel<<<1, 1024, 0, stream>>>(rois, perm, N);
        dim3 tgrid(HW / 32, C_TOT / 32, 2);
        dim3 tblk(32, 8);
        nchw_to_nhwc_bf16_kernel<<<tgrid, tblk, 0, stream>>>(feat, featT);
        roi_align_nhwc_kernel<<<N, 512, 0, stream>>>(featT, rois, perm, out, N, use_perm);
    } else {
        int total  = N * CG * S_TOT;
        int blocks = (total + 255) / 256;
        roi_align_direct_kernel<<<blocks, 256, 0, stream>>>(feat, rois, out, N);
    }
}

// Round 6
// 61.121 us; speedup vs baseline: 1.1500x; 1.1500x over previous
//
#include <hip/hip_runtime.h>
#include <hip/hip_bf16.h>

// ROI Align fp32, NCHW input (B=2, C=256, H=W=200), pooled 7x7, SAMPLE_NUM=2,
// SPATIAL_SCALE=0.25, ROI_END_MODE=1.
//
// Round 6: de-confounded XCD-chunking test. Round 5's bitonic sort was ~7-13us
// of serial single-block time, masking any gather gain. Replace with a ~1-2us
// counting-bin permutation (32 buckets = batch x 4x4 spatial grid), keep the
// chunked XCD block mapping. If the gather doesn't improve now, the ~10 TB/s
// gather wall is XCD-locality-insensitive and we revert to round-4 pipeline.
//   Phase 0: roi_bin_kernel -> perm[] (1 block, ~2 barriers)
//   Phase 1: NCHW fp32 -> NHWC bf16 transpose into d_ws (41 MB)
//   Phase 2: gather (512 thr / ROI), chunked XCD mapping via perm

constexpr int C_TOT  = 256;
constexpr int H_FEAT = 200;
constexpr int W_FEAT = 200;
constexpr int HW     = H_FEAT * W_FEAT;
constexpr int S_TOT  = 49;             // 7*7 pooled cells
constexpr size_t FEATT_BYTES = (size_t)2 * HW * C_TOT * sizeof(unsigned short); // 40.96 MB
constexpr int NXCD = 8;
constexpr int NBUCKET = 32;            // b(1) x qy(2) x qx(2) bits

// ---------------------------------------------------------------- ROI binning
// Single block, 1024 threads. perm[] = ROI indices grouped by
// (batch, coarse 4x4 spatial tile of ROI center). Intra-bucket order is
// atomic-arrival order (non-deterministic) but output is per-ROI and
// order-independent, so the final result is deterministic.
__global__ __launch_bounds__(1024) void roi_bin_kernel(
    const float* __restrict__ rois, int* __restrict__ perm, int N)
{
    __shared__ int hist[NBUCKET];
    __shared__ int base[NBUCKET];
    __shared__ int cnt[NBUCKET];
    int t = threadIdx.x;

    if (t < NBUCKET) { hist[t] = 0; cnt[t] = 0; }
    __syncthreads();

    int bucket = -1;
    if (t < N) {
        const float* r = rois + (size_t)t * 5;
        int   b  = (int)r[0];
        float cx = (r[1] + r[3]) * 0.5f * 0.25f;   // feature-space center
        float cy = (r[2] + r[4]) * 0.5f * 0.25f;
        int qx = min(max((int)(cx * (4.0f / 200.0f)), 0), 3);
        int qy = min(max((int)(cy * (4.0f / 200.0f)), 0), 3);
        bucket = ((b & 1) << 4) | (qy << 2) | qx;
        atomicAdd(&hist[bucket], 1);
    }
    __syncthreads();

    if (t == 0) {
        int acc = 0;
        for (int i = 0; i < NBUCKET; ++i) { base[i] = acc; acc += hist[i]; }
    }
    __syncthreads();

    if (t < N) {
        int pos = base[bucket] + atomicAdd(&cnt[bucket], 1);
        perm[pos] = t;
    }
}

// ---------------------------------------------------------------- transpose
// feat[b][c][s] (fp32) -> featT[b][s][c] (bf16, RNE).
__global__ __launch_bounds__(256) void nchw_to_nhwc_bf16_kernel(
    const float* __restrict__ feat,
    unsigned short* __restrict__ featT)
{
    __shared__ float tile[32][33];
    int tx = threadIdx.x;        // 0..31
    int ty = threadIdx.y;        // 0..7
    int s0 = blockIdx.x * 32;
    int c0 = blockIdx.y * 32;
    int b  = blockIdx.z;

    const float* src = feat + ((size_t)b * C_TOT) * HW;
    #pragma unroll
    for (int i = 0; i < 4; ++i) {
        int r = ty + i * 8;      // channel within tile
        tile[r][tx] = src[(size_t)(c0 + r) * HW + (s0 + tx)];
    }
    __syncthreads();
    unsigned short* dst = featT + ((size_t)b * HW) * C_TOT;
    #pragma unroll
    for (int i = 0; i < 4; ++i) {
        int r = ty + i * 8;      // spatial within tile
        float x = tile[tx][r];
        unsigned int u = __float_as_uint(x);
        unsigned int rb = (u + 0x7fffu + ((u >> 16) & 1u)) >> 16;   // RNE
        dst[(size_t)(s0 + r) * C_TOT + (c0 + tx)] = (unsigned short)rb;
    }
}

// ---------------------------------------------------------------- gather
__global__ __launch_bounds__(512) void roi_align_nhwc_kernel(
    const unsigned short* __restrict__ featT,
    const float* __restrict__ rois,
    const int* __restrict__ perm,
    float* __restrict__ out,
    int N, int use_perm)
{
    __shared__ alignas(16) float tile[C_TOT * S_TOT];   // [c][s] == output order

    int n;
    if (use_perm) {
        // chunked XCD transform: XCD x gets sorted ranks [x*chunk, (x+1)*chunk)
        int chunk = (N + NXCD - 1) / NXCD;
        int rank  = (blockIdx.x & (NXCD - 1)) * chunk + (blockIdx.x >> 3);
        if (rank >= N) rank = blockIdx.x;
        n = perm[rank];
    } else {
        n = blockIdx.x;
    }

    int tid  = threadIdx.x;
    int wave = tid >> 6;         // 0..7
    int lane = tid & 63;

    const float* r = rois + (size_t)n * 5;
    int   b  = (int)r[0];
    float x1 = r[1] * 0.25f;
    float y1 = r[2] * 0.25f;
    float x2 = (r[3] + 1.0f) * 0.25f;
    float y2 = (r[4] + 1.0f) * 0.25f;
    float bin_w = fmaxf(x2 - x1, 1.0f) * (1.0f / 7.0f);
    float bin_h = fmaxf(y2 - y1, 1.0f) * (1.0f / 7.0f);

    const unsigned short* fbase =
        featT + (size_t)b * HW * C_TOT + (size_t)lane * 4;

    for (int s = wave; s < S_TOT; s += 8) {
        int ph = s / 7;
        int pw = s - ph * 7;

        int   yoff[2][2];
        int   xoff[2][2];
        float wy[2][2], wx[2][2];
        #pragma unroll
        for (int i = 0; i < 2; ++i) {
            float gy  = (float)(2 * ph + i);
            float cy  = y1 + bin_h * ((gy + 0.5f) * 0.5f);
            bool  vy  = (cy >= -1.0f) && (cy <= (float)H_FEAT);
            float ccy = fminf(fmaxf(cy, 0.0f), (float)(H_FEAT - 1));
            int   ylo = (int)ccy;
            int   yhi = min(ylo + 1, H_FEAT - 1);
            float fy  = ccy - (float)ylo;
            yoff[i][0] = ylo * W_FEAT;
            yoff[i][1] = yhi * W_FEAT;
            // fold 0.5 per axis -> product carries the 0.25 sample-average
            wy[i][0] = vy ? (1.0f - fy) * 0.5f : 0.0f;
            wy[i][1] = vy ? fy * 0.5f          : 0.0f;

            float gx  = (float)(2 * pw + i);
            float cx  = x1 + bin_w * ((gx + 0.5f) * 0.5f);
            bool  vx  = (cx >= -1.0f) && (cx <= (float)W_FEAT);
            float ccx = fminf(fmaxf(cx, 0.0f), (float)(W_FEAT - 1));
            int   xlo = (int)ccx;
            int   xhi = min(xlo + 1, W_FEAT - 1);
            float fx  = ccx - (float)xlo;
            xoff[i][0] = xlo;
            xoff[i][1] = xhi;
            wx[i][0] = vx ? (1.0f - fx) * 0.5f : 0.0f;
            wx[i][1] = vx ? fx * 0.5f          : 0.0f;
        }

        float4 acc = make_float4(0.f, 0.f, 0.f, 0.f);
        #pragma unroll
        for (int iy = 0; iy < 2; ++iy)
        #pragma unroll
        for (int jy = 0; jy < 2; ++jy)
        #pragma unroll
        for (int ix = 0; ix < 2; ++ix)
        #pragma unroll
        for (int jx = 0; jx < 2; ++jx) {
            float w = wy[iy][jy] * wx[ix][jx];
            const ushort4 v = *reinterpret_cast<const ushort4*>(
                fbase + (size_t)(yoff[iy][jy] + xoff[ix][jx]) * C_TOT);
            float f0 = __uint_as_float((unsigned int)v.x << 16);
            float f1 = __uint_as_float((unsigned int)v.y << 16);
            float f2 = __uint_as_float((unsigned int)v.z << 16);
            float f3 = __uint_as_float((unsigned int)v.w << 16);
            acc.x = fmaf(w, f0, acc.x);
            acc.y = fmaf(w, f1, acc.y);
            acc.z = fmaf(w, f2, acc.z);
            acc.w = fmaf(w, f3, acc.w);
        }

        int c = lane * 4;
        tile[(c + 0) * S_TOT + s] = acc.x;
        tile[(c + 1) * S_TOT + s] = acc.y;
        tile[(c + 2) * S_TOT + s] = acc.z;
        tile[(c + 3) * S_TOT + s] = acc.w;
    }
    __syncthreads();

    // Linear float4 store: tile flat layout == out[n] flat layout.
    const float4* t4 = reinterpret_cast<const float4*>(tile);
    float4* o4 = reinterpret_cast<float4*>(out + (size_t)n * (C_TOT * S_TOT));
    constexpr int Q = C_TOT * S_TOT / 4;   // 3136
    for (int q = tid; q < Q; q += 512)
        o4[q] = t4[q];
}

// ---------------------------------------------------------------- fp32 fallback
constexpr int CPT = 4;
constexpr int CG  = C_TOT / CPT;

__global__ __launch_bounds__(256) void roi_align_direct_kernel(
    const float* __restrict__ feat,
    const float* __restrict__ rois,
    float* __restrict__ out,
    int N)
{
    int t = blockIdx.x * 256 + threadIdx.x;
    int total = N * CG * S_TOT;
    if (t >= total) return;

    int s   = t % S_TOT;
    int rem = t / S_TOT;
    int c0  = rem % CG;
    int n   = rem / CG;
    int ph  = s / 7;
    int pw  = s - ph * 7;

    const float* r = rois + (size_t)n * 5;
    int   b  = (int)r[0];
    float x1 = r[1] * 0.25f;
    float y1 = r[2] * 0.25f;
    float x2 = (r[3] + 1.0f) * 0.25f;
    float y2 = (r[4] + 1.0f) * 0.25f;
    float bin_w = fmaxf(x2 - x1, 1.0f) * (1.0f / 7.0f);
    float bin_h = fmaxf(y2 - y1, 1.0f) * (1.0f / 7.0f);

    int   roff[2][2], coff[2][2];
    float wy[2][2], wx[2][2];
    #pragma unroll
    for (int i = 0; i < 2; ++i) {
        float gy  = (float)(2 * ph + i);
        float cy  = y1 + bin_h * ((gy + 0.5f) * 0.5f);
        bool  vy  = (cy >= -1.0f) && (cy <= (float)H_FEAT);
        float ccy = fminf(fmaxf(cy, 0.0f), (float)(H_FEAT - 1));
        int   ylo = (int)ccy;
        int   yhi = min(ylo + 1, H_FEAT - 1);
        float fy  = ccy - (float)ylo;
        roff[i][0] = ylo * W_FEAT;
        roff[i][1] = yhi * W_FEAT;
        wy[i][0] = vy ? (1.0f - fy) : 0.0f;
        wy[i][1] = vy ? fy          : 0.0f;

        float gx  = (float)(2 * pw + i);
        float cx  = x1 + bin_w * ((gx + 0.5f) * 0.5f);
        bool  vx  = (cx >= -1.0f) && (cx <= (float)W_FEAT);
        float ccx = fminf(fmaxf(cx, 0.0f), (float)(W_FEAT - 1));
        int   xlo = (int)ccx;
        int   xhi = min(xlo + 1, W_FEAT - 1);
        float fx  = ccx - (float)xlo;
        coff[i][0] = xlo;
        coff[i][1] = xhi;
        wx[i][0] = vx ? (1.0f - fx) : 0.0f;
        wx[i][1] = vx ? fx          : 0.0f;
    }

    float w16[16];
    int   o16[16];
    #pragma unroll
    for (int iy = 0; iy < 2; ++iy)
    #pragma unroll
    for (int ix = 0; ix < 2; ++ix)
    #pragma unroll
    for (int jy = 0; jy < 2; ++jy)
    #pragma unroll
    for (int jx = 0; jx < 2; ++jx) {
        int idx = ((iy * 2 + ix) * 2 + jy) * 2 + jx;
        w16[idx] = wy[iy][jy] * wx[ix][jx];
        o16[idx] = roff[iy][jy] + coff[ix][jx];
    }

    size_t base  = ((size_t)b * C_TOT + c0) * HW;
    size_t obase = (size_t)n * (C_TOT * S_TOT) + (size_t)c0 * S_TOT + s;

    #pragma unroll
    for (int k = 0; k < CPT; ++k) {
        const float* f = feat + base + (size_t)k * CG * HW;
        float acc = 0.0f;
        #pragma unroll
        for (int j = 0; j < 16; ++j)
            acc = fmaf(w16[j], f[o16[j]], acc);
        out[obase + (size_t)k * (CG * S_TOT)] = acc * 0.25f;
    }
}

extern "C" void kernel_launch(void* const* d_in, const int* in_sizes, int n_in,
                              void* d_out, int out_size, void* d_ws, size_t ws_size,
                              hipStream_t stream) {
    const float* feat = (const float*)d_in[0];
    const float* rois = (const float*)d_in[1];
    float* out = (float*)d_out;
    int N = in_sizes[1] / 5;

    size_t need = FEATT_BYTES + 4096;
    if (ws_size >= need) {
        unsigned short* featT = (unsigned short*)d_ws;
        int* perm = (int*)((char*)d_ws + FEATT_BYTES);
        int use_perm = (N <= 1024) ? 1 : 0;
        if (use_perm)
            roi_bin_kernel<<<1, 1024, 0, stream>>>(rois, perm, N);
        dim3 tgrid(HW / 32, C_TOT / 32, 2);
        dim3 tblk(32, 8);
        nchw_to_nhwc_bf16_kernel<<<tgrid, tblk, 0, stream>>>(feat, featT);
        roi_align_nhwc_kernel<<<N, 512, 0, stream>>>(featT, rois, perm, out, N, use_perm);
    } else {
        int total  = N * CG * S_TOT;
        int blocks = (total + 255) / 256;
        roi_align_direct_kernel<<<blocks, 256, 0, stream>>>(feat, rois, out, N);
    }
}